// Round 4
// 245.329 us; speedup vs baseline: 1.2737x; 1.2737x over previous
//
#include <hip/hip_runtime.h>
#include <hip/hip_bf16.h>

#define EPS 1e-6f
#define INV_TEMP 0.31622776601683794f   // 1/sqrt(10), folded into M = Wq^T Wk / T

typedef float f32x4 __attribute__((ext_vector_type(4)));
typedef short short8v __attribute__((ext_vector_type(8)));
typedef unsigned uint4v __attribute__((ext_vector_type(4)));

#define MFMA(a,b,c) __builtin_amdgcn_mfma_f32_16x16x32_bf16(a,b,c,0,0,0)

// ---------- B-fragment table in d_ws (bf16 shorts), 55 frags x 512 shorts ----------
// f=0,1 : M_hi nt0,1 — block-diag(3) of bf16(M), M=Wq^T Wk/T, [32k x 32n]
// f=2,3 : M_lo nt0,1 — block-diag(3) of bf16(M - M_hi)   (hi/lo pair => fp32-accurate M)
// f=4,5 : Wv  nt0,1  — block-diag(3) of Wv
// f=6,7 : W1 nt0,1 (K=30,N=30)   f=8,9: W2 nt0,1
// f=10+kt*6+nt : W1p (K=90,N=90) f=28+kt*6+nt: W2p   f=46+kt*3+nt: Wc1 (K=90,N=45)
// prep zeroes all out-of-range K/N rows -> A-fragment k-pad contributes 0 if finite.
#define NFRAG 55

// ---------- per-wave LDS layout (offsets in shorts) ----------
// X30 [48x40] rows b*16+r, cols s*10+d (+2 zero pad); stages 1..4
// KT/VH [48x30] rows b*16+r, cols t*10+d; stages 1,3; alias H30/H90/C1T/X90-head
// H30 [48x40] stages 2,4; H90 [16x104] stage 5; C1T [16x48] classifier
// X90 [16x104] stages 4..6; tail [4800,5504) zeroed once at start (k-pad, never data)
#define X30   0
#define KT    1920
#define VH    3360
#define H30   1920
#define H90   1920
#define C1T   1920
#define X90   3840
#define WSM   5504     // shorts per wave = 11008 B -> 22016 B/block -> 7 blocks/CU

#define S_P   40       // 80 B rows (16B-aligned, conflict-free b128)
#define S_X9  104      // 208 B rows (16B-aligned, conflict-free b128)
#define S_C1  48
#define S_KT  30       // KT/VH row stride (scalar dword access only)

// ---------------- bf16 conversion ----------------
__device__ __forceinline__ unsigned short f2b_sw(float x){       // RNE, host-prep use
  unsigned u = __float_as_uint(x);
  u += 0x7fffu + ((u>>16)&1u);
  return (unsigned short)(u>>16);
}
__device__ __forceinline__ unsigned pack2(float a, float b){     // low=a, high=b, RNE
  float2 t; t.x = a; t.y = b;
  __hip_bfloat162 h = __float22bfloat162_rn(t);
  unsigned u; __builtin_memcpy(&u, &h, 4); return u;
}
__device__ __forceinline__ unsigned short f2b(float x){
  __hip_bfloat16 h = __float2bfloat16(x);
  unsigned short u; __builtin_memcpy(&u, &h, 2); return u;
}
__device__ __forceinline__ float b2f(unsigned u16){              // low 16 bits -> f32
  return __uint_as_float(u16<<16);
}
__device__ __forceinline__ short8v ldB(const unsigned short* __restrict__ wf, int f, int wtid){
  return *(const short8v*)(wf + f*512 + wtid*8);                 // 16B/lane
}
__device__ __forceinline__ short8v ldA(const unsigned short* sm, int rowbase, int stride, int koff, int wtid){
  return *(const short8v*)(sm + (rowbase + (wtid&15))*stride + koff + (wtid>>4)*8);
}
__device__ __forceinline__ float qsum16(float v){                // sum across 16-lane quad
  v += __shfl_xor(v,1,64); v += __shfl_xor(v,2,64);
  v += __shfl_xor(v,4,64); v += __shfl_xor(v,8,64);
  return v;
}

// ---------------- prep: bake weights into B-fragment order ----------------
__global__ void prep_kernel(const float* __restrict__ Wq, const float* __restrict__ Wk,
                            const float* __restrict__ Wv, const float* __restrict__ W1,
                            const float* __restrict__ W2, const float* __restrict__ W1p,
                            const float* __restrict__ W2p, const float* __restrict__ Wc1,
                            unsigned short* __restrict__ wf)
{
  int t = blockIdx.x*blockDim.x + threadIdx.x;
  if (t >= NFRAG*512) return;
  int f = t>>9, e = t&511, lane = e>>3, j = e&7;
  int n = lane&15, kk = (lane>>4)*8 + j;
  float val = 0.f;
  if (f < 6){
    // block-diagonal attention operators, [32 k x 32 n]
    int ntb = (f<2) ? f : (f<4) ? (f-2) : (f-4);
    int gn = ntb*16 + n;          // n = t*10+d   (0..29 valid)
    int gk = kk;                  // k = t'*10+d' (0..29 valid)
    if (gn < 30 && gk < 30 && (gn/10) == (gk/10)){
      int dn = gn%10, dk = gk%10;
      if (f < 4){                 // M[dn,dk] = sum_e Wq[e,dn]*Wk[e,dk] / T
        float a = 0.f;
        for (int ee=0; ee<10; ++ee) a += Wq[ee*10+dn]*Wk[ee*10+dk];
        a *= INV_TEMP;
        float hi = b2f(f2b_sw(a));
        val = (f < 2) ? a : (a - hi);       // hi frag stores bf16(a); lo stores residual
      } else val = Wv[dn*10+dk];  // vh = v @ Wv^T
    }
  } else {
    const float* src; int K, N, kt, nt;
    if (f < 8)      { src = W1;  K=30; N=30; kt=0; nt=f-6; }
    else if (f < 10){ src = W2;  K=30; N=30; kt=0; nt=f-8; }
    else if (f < 28){ int g=f-10; src = W1p; K=90; N=90; kt=g/6; nt=g%6; }
    else if (f < 46){ int g=f-28; src = W2p; K=90; N=90; kt=g/6; nt=g%6; }
    else            { int g=f-46; src = Wc1; K=90; N=45; kt=g/3; nt=g%3; }
    int gn = nt*16 + n, gk = kt*32 + kk;
    if (gn < N && gk < K) val = src[gn*K + gk];   // B[k][n] = W[n][k]
  }
  wf[t] = f2b_sw(val);
}

// ---------------- per-branch attention (VALU, lanes 0..47 of the wave) ----------------
// query == residual (q slice in stage1, x30 in stage3); scores via fp32 qv . bf16 KT
template<bool S1>
__device__ __forceinline__ void attn_phase(unsigned short* sm, int wtid, int b,
    const float* res, const float* __restrict__ g, const float* __restrict__ bb)
{
  if (wtid >= 48) return;
  int r = wtid/3, s = wtid - 3*r;
  float qv[10], at[3];
  if (S1){
    #pragma unroll
    for (int d=0;d<10;++d) qv[d] = res[d];        // fp32 residual from registers
  } else {
    const unsigned* p = (const unsigned*)(sm + X30 + (b*16+r)*S_P + s*10);
    #pragma unroll
    for (int e=0;e<5;++e){ unsigned u=p[e]; qv[2*e]=b2f(u&0xffffu); qv[2*e+1]=b2f(u>>16); }
  }
  const unsigned* kp = (const unsigned*)sm + (KT>>1) + (b*16+r)*15;
  #pragma unroll
  for (int t=0;t<3;++t){
    float a = 0.f;
    #pragma unroll
    for (int e=0;e<5;++e){ unsigned u = kp[t*5+e];
      a = fmaf(qv[2*e],   b2f(u&0xffffu), a);
      a = fmaf(qv[2*e+1], b2f(u>>16),    a); }
    at[t] = a;                                    // M already carries 1/sqrt(10)
  }
  float ov[10];
  #pragma unroll
  for (int d=0;d<10;++d) ov[d] = qv[d];           // residual
  const unsigned* vp = (const unsigned*)sm + (VH>>1) + (b*16+r)*15;
  #pragma unroll
  for (int t=0;t<3;++t){
    #pragma unroll
    for (int e=0;e<5;++e){ unsigned u = vp[t*5+e];
      ov[2*e]   = fmaf(at[t], b2f(u&0xffffu), ov[2*e]);
      ov[2*e+1] = fmaf(at[t], b2f(u>>16),    ov[2*e+1]); }
  }
  float sum=0.f, sq=0.f;
  #pragma unroll
  for (int d=0;d<10;++d){ sum += ov[d]; sq = fmaf(ov[d],ov[d],sq); }
  float mm = sum*0.1f, rs = rsqrtf(sq*0.1f - mm*mm + EPS);
  unsigned* wp = (unsigned*)(sm + X30 + (b*16+r)*S_P + s*10);
  #pragma unroll
  for (int e=0;e<5;++e){
    float z0 = fmaf((ov[2*e]-mm)*rs,   g[2*e],   bb[2*e]);
    float z1 = fmaf((ov[2*e+1]-mm)*rs, g[2*e+1], bb[2*e+1]);
    wp[e] = pack2(z0, z1);
  }
}

// ---------------- PFF30 on all 48 branch-rows ----------------
template<bool TO_X90>
__device__ __forceinline__ void pff30(unsigned short* sm, int wtid, const unsigned short* __restrict__ wf,
  const float* __restrict__ b1, const float* __restrict__ b2,
  const float* __restrict__ g, const float* __restrict__ bb)
{
  const int m15 = wtid & 15, quad = wtid >> 4;
  const bool c1ok = (m15 < 14);                 // col 16+m15 < 30
  float bi0 = b1[m15], bi1 = c1ok ? b1[16+m15] : 0.f;
  float b20 = b2[m15], b21 = c1ok ? b2[16+m15] : 0.f;
  float g0  = g[m15],  g1  = c1ok ? g[16+m15]  : 0.f;
  float e0  = bb[m15], e1  = c1ok ? bb[16+m15] : 0.f;
  short8v B10 = ldB(wf,6,wtid), B11 = ldB(wf,7,wtid), B20 = ldB(wf,8,wtid), B21 = ldB(wf,9,wtid);
  #pragma unroll 1
  for (int mt=0; mt<3; ++mt){
    short8v A = ldA(sm + X30, mt*16, S_P, 0, wtid);
    f32x4 C0 = {0.f,0.f,0.f,0.f}, C1 = {0.f,0.f,0.f,0.f};
    C0 = MFMA(A, B10, C0);
    C1 = MFMA(A, B11, C1);
    #pragma unroll
    for (int rg=0; rg<4; ++rg){
      int row = mt*16 + quad*4 + rg;
      sm[H30 + row*S_P + m15]    = f2b(fmaxf(C0[rg]+bi0, 0.f));
      sm[H30 + row*S_P + 16+m15] = f2b(fmaxf(C1[rg]+bi1, 0.f));  // cols 30,31 -> 0
    }
    short8v A2 = ldA(sm + H30, mt*16, S_P, 0, wtid);
    f32x4 D0 = {0.f,0.f,0.f,0.f}, D1 = {0.f,0.f,0.f,0.f};
    D0 = MFMA(A2, B20, D0);
    D1 = MFMA(A2, B21, D1);
    float y0[4], y1[4];
    #pragma unroll
    for (int rg=0; rg<4; ++rg){
      int row = mt*16 + quad*4 + rg;
      float r0 = b2f(sm[X30 + row*S_P + m15]);
      float r1 = c1ok ? b2f(sm[X30 + row*S_P + 16+m15]) : 0.f;
      y0[rg] = D0[rg] + b20 + r0;
      y1[rg] = c1ok ? (D1[rg] + b21 + r1) : 0.f;
    }
    #pragma unroll
    for (int rg=0; rg<4; ++rg){
      float sr = qsum16(y0[rg] + y1[rg]);
      float qr = qsum16(y0[rg]*y0[rg] + y1[rg]*y1[rg]);
      float mm = sr * (1.f/30.f);
      float rs = rsqrtf(qr*(1.f/30.f) - mm*mm + EPS);
      float z0 = fmaf((y0[rg]-mm)*rs, g0, e0);
      float z1 = fmaf((y1[rg]-mm)*rs, g1, e1);   // 0 when !c1ok
      if (!TO_X90){
        int row = mt*16 + quad*4 + rg;
        sm[X30 + row*S_P + m15]    = f2b(z0);
        sm[X30 + row*S_P + 16+m15] = f2b(z1);    // cols 30,31 stay 0
      } else {
        int rr = quad*4 + rg;                    // brow = mt*16+rr -> x90[rr][mt*30+col]
        sm[X90 + rr*S_X9 + mt*30 + m15]    = f2b(z0);
        sm[X90 + rr*S_X9 + mt*30 + 16+m15] = f2b(z1);
      }
    }
  }
}

// ---------------- PFF90 on x90 [16 x 90] ----------------
__device__ __forceinline__ void pff90(unsigned short* sm, int wtid, const unsigned short* __restrict__ wf,
  const float* __restrict__ b1p, const float* __restrict__ b2p,
  const float* __restrict__ g1, const float* __restrict__ bb1)
{
  const int m15 = wtid & 15, quad = wtid >> 4;
  short8v A0 = ldA(sm+X90, 0, S_X9, 0,  wtid);
  short8v A1 = ldA(sm+X90, 0, S_X9, 32, wtid);
  short8v A2 = ldA(sm+X90, 0, S_X9, 64, wtid);
  #pragma unroll
  for (int nt=0; nt<6; ++nt){
    f32x4 c = {0.f,0.f,0.f,0.f};
    c = MFMA(A0, ldB(wf, 10+nt, wtid), c);
    c = MFMA(A1, ldB(wf, 16+nt, wtid), c);
    c = MFMA(A2, ldB(wf, 22+nt, wtid), c);
    int col = nt*16 + m15;
    float bi = (col < 90) ? b1p[col] : 0.f;
    #pragma unroll
    for (int rg=0; rg<4; ++rg)
      sm[H90 + (quad*4+rg)*S_X9 + col] = f2b(fmaxf(c[rg]+bi, 0.f));  // cols>=90 -> 0
  }
  short8v H0 = ldA(sm+H90, 0, S_X9, 0,  wtid);
  short8v H1 = ldA(sm+H90, 0, S_X9, 32, wtid);
  short8v H2 = ldA(sm+H90, 0, S_X9, 64, wtid);
  float y[6][4];
  #pragma unroll
  for (int nt=0; nt<6; ++nt){
    f32x4 d = {0.f,0.f,0.f,0.f};
    d = MFMA(H0, ldB(wf, 28+nt, wtid), d);
    d = MFMA(H1, ldB(wf, 34+nt, wtid), d);
    d = MFMA(H2, ldB(wf, 40+nt, wtid), d);
    int col = nt*16 + m15;
    bool ok = (col < 90);
    float b2v = ok ? b2p[col] : 0.f;
    #pragma unroll
    for (int rg=0; rg<4; ++rg){
      float rv = ok ? b2f(sm[X90 + (quad*4+rg)*S_X9 + col]) : 0.f;
      y[nt][rg] = ok ? (d[rg] + b2v + rv) : 0.f;
    }
  }
  #pragma unroll
  for (int rg=0; rg<4; ++rg){
    float ps = 0.f, pq = 0.f;
    #pragma unroll
    for (int nt=0; nt<6; ++nt){ ps += y[nt][rg]; pq = fmaf(y[nt][rg], y[nt][rg], pq); }
    float sr = qsum16(ps), qr = qsum16(pq);
    float mm = sr*(1.f/90.f);
    float rs = rsqrtf(qr*(1.f/90.f) - mm*mm + EPS);
    int row = quad*4 + rg;
    #pragma unroll
    for (int nt=0; nt<6; ++nt){
      int col = nt*16 + m15;
      if (col < 90)
        sm[X90 + row*S_X9 + col] = f2b(fmaf((y[nt][rg]-mm)*rs, g1[col], bb1[col]));
    }
  }
}

// ---------------- classifier + softmax ----------------
__device__ __forceinline__ void classifier(unsigned short* sm, int wtid, const unsigned short* __restrict__ wf,
  const float* __restrict__ bc1, const float* __restrict__ Wc2, const float* __restrict__ bc2,
  float* __restrict__ out, int row0)
{
  const int m15 = wtid & 15, quad = wtid >> 4;
  short8v A0 = ldA(sm+X90, 0, S_X9, 0,  wtid);
  short8v A1 = ldA(sm+X90, 0, S_X9, 32, wtid);
  short8v A2 = ldA(sm+X90, 0, S_X9, 64, wtid);
  #pragma unroll
  for (int nt=0; nt<3; ++nt){
    f32x4 c = {0.f,0.f,0.f,0.f};
    c = MFMA(A0, ldB(wf, 46+nt, wtid), c);
    c = MFMA(A1, ldB(wf, 49+nt, wtid), c);
    c = MFMA(A2, ldB(wf, 52+nt, wtid), c);
    int col = nt*16 + m15;
    float bi = (col < 45) ? bc1[col] : 0.f;
    #pragma unroll
    for (int rg=0; rg<4; ++rg)
      sm[C1T + (quad*4+rg)*S_C1 + col] = f2b(fmaxf(c[rg]+bi, 0.f));
  }
  int row = m15, p = quad;
  int i0 = p*12, cnt = (p<3) ? 12 : 9;
  float lg0=0.f, lg1=0.f, lg2=0.f;
  for (int ii=0; ii<cnt; ++ii){
    float cv = b2f(sm[C1T + row*S_C1 + i0+ii]);
    lg0 = fmaf(cv, Wc2[     i0+ii], lg0);
    lg1 = fmaf(cv, Wc2[45 + i0+ii], lg1);
    lg2 = fmaf(cv, Wc2[90 + i0+ii], lg2);
  }
  lg0 += __shfl_xor(lg0,16,64); lg0 += __shfl_xor(lg0,32,64);
  lg1 += __shfl_xor(lg1,16,64); lg1 += __shfl_xor(lg1,32,64);
  lg2 += __shfl_xor(lg2,16,64); lg2 += __shfl_xor(lg2,32,64);
  lg0 += bc2[0]; lg1 += bc2[1]; lg2 += bc2[2];
  float mx = fmaxf(lg0, fmaxf(lg1,lg2));
  float x0 = __expf(lg0-mx), x1 = __expf(lg1-mx), x2 = __expf(lg2-mx);
  float inv = 1.f/(x0+x1+x2);
  if (p == 0){
    float* o = out + (size_t)(row0+row)*3;
    o[0]=x0*inv; o[1]=x1*inv; o[2]=x2*inv;
  }
}

// ---------------- main: 128 threads = 2 independent waves, 16 rows each ----------------
__global__ __launch_bounds__(128, 4) void moct_kernel(
  const float* __restrict__ q, const float* __restrict__ k, const float* __restrict__ v,
  const float* __restrict__ g_mha, const float* __restrict__ b_mha,
  const float* __restrict__ b1, const float* __restrict__ b2,
  const float* __restrict__ g_pff, const float* __restrict__ b_pff,
  const float* __restrict__ b1p, const float* __restrict__ b2p,
  const float* __restrict__ g_pff1, const float* __restrict__ b_pff1,
  const float* __restrict__ bc1, const float* __restrict__ Wc2, const float* __restrict__ bc2,
  const unsigned short* __restrict__ wf,
  float* __restrict__ out)
{
  __shared__ __align__(16) unsigned short smem[2*WSM];
  const int tid = threadIdx.x, wv = tid>>6, wtid = tid&63;
  unsigned short* sm = smem + wv*WSM;
  const int m15 = wtid & 15, quad = wtid >> 4;
  const int row0 = blockIdx.x*32 + wv*16;

  // X30 k-pad (shorts 30,31 of each of 48 rows) = 0 once; never overwritten after.
  if (wtid < 48) *(unsigned*)(sm + X30 + wtid*S_P + 30) = 0u;
  // X90 tail [4800,5504): never touched by data writes (VH ends at 4800); zero once.
  #pragma unroll
  for (int i=0;i<6;++i){ int idx = wtid + i*64; if (idx < 352) ((unsigned*)sm)[2400+idx] = 0u; }

  // ---- stage 1: project k,v with block-diag B (single batched load phase) ----
  {
    const float* kbase = k + (size_t)(row0+m15)*90;
    const float* vbase = v + (size_t)(row0+m15)*90;
    uint4v uk[3], uv[3];
    #pragma unroll
    for (int b=0;b<3;++b){
      const float2* kp = (const float2*)(kbase + b*30 + quad*8);
      const float2* vp = (const float2*)(vbase + b*30 + quad*8);
      float2 k0=kp[0], k1=kp[1], k2=kp[2];
      float2 v0=vp[0], v1=vp[1], v2=vp[2];
      float2 k3, v3;
      if (b==2 && quad==3){ k3=make_float2(0.f,0.f); v3=make_float2(0.f,0.f); } // k=30,31 pad; avoids OOB on last row
      else                { k3=kp[3]; v3=vp[3]; }
      uk[b][0]=pack2(k0.x,k0.y); uk[b][1]=pack2(k1.x,k1.y);
      uk[b][2]=pack2(k2.x,k2.y); uk[b][3]=pack2(k3.x,k3.y);
      uv[b][0]=pack2(v0.x,v0.y); uv[b][1]=pack2(v1.x,v1.y);
      uv[b][2]=pack2(v2.x,v2.y); uv[b][3]=pack2(v3.x,v3.y);
    }
    float res[3][10];
    if (wtid < 48){
      int r = wtid/3, s = wtid - 3*r;
      #pragma unroll
      for (int b=0;b<3;++b){
        const float2* rp = (const float2*)(q + (size_t)(row0+r)*90 + b*30 + s*10);
        #pragma unroll
        for (int e=0;e<5;++e){ float2 t2=rp[e]; res[b][2*e]=t2.x; res[b][2*e+1]=t2.y; }
      }
    }
    short8v Bkh0=ldB(wf,0,wtid), Bkh1=ldB(wf,1,wtid);
    short8v Bkl0=ldB(wf,2,wtid), Bkl1=ldB(wf,3,wtid);
    short8v Bv0 =ldB(wf,4,wtid), Bv1 =ldB(wf,5,wtid);
    #pragma unroll
    for (int b=0;b<3;++b){
      short8v A;
      __builtin_memcpy(&A,&uk[b],16);
      f32x4 c0={0.f,0.f,0.f,0.f}, c1={0.f,0.f,0.f,0.f};
      c0 = MFMA(A,Bkh0,c0); c0 = MFMA(A,Bkl0,c0);
      c1 = MFMA(A,Bkh1,c1); c1 = MFMA(A,Bkl1,c1);
      #pragma unroll
      for (int rg=0;rg<4;++rg){
        int row = b*16 + quad*4 + rg;
        sm[KT + row*S_KT + m15] = f2b(c0[rg]);
        if (m15 < 14) sm[KT + row*S_KT + 16+m15] = f2b(c1[rg]);
      }
      __builtin_memcpy(&A,&uv[b],16);
      f32x4 d0={0.f,0.f,0.f,0.f}, d1={0.f,0.f,0.f,0.f};
      d0 = MFMA(A,Bv0,d0); d1 = MFMA(A,Bv1,d1);
      #pragma unroll
      for (int rg=0;rg<4;++rg){
        int row = b*16 + quad*4 + rg;
        sm[VH + row*S_KT + m15] = f2b(d0[rg]);
        if (m15 < 14) sm[VH + row*S_KT + 16+m15] = f2b(d1[rg]);
      }
    }
    attn_phase<true>(sm, wtid, 0, res[0], g_mha, b_mha);
    attn_phase<true>(sm, wtid, 1, res[1], g_mha, b_mha);
    attn_phase<true>(sm, wtid, 2, res[2], g_mha, b_mha);
  }

  // ---- stage 2: PFF30 (in-place x30) ----
  pff30<false>(sm, wtid, wf, b1, b2, g_pff, b_pff);

  // ---- stage 3: MHA(x,x,x); A straight from X30, no repack ----
  {
    short8v Bkh0=ldB(wf,0,wtid), Bkh1=ldB(wf,1,wtid);
    short8v Bkl0=ldB(wf,2,wtid), Bkl1=ldB(wf,3,wtid);
    short8v Bv0 =ldB(wf,4,wtid), Bv1 =ldB(wf,5,wtid);
    #pragma unroll
    for (int mt=0; mt<3; ++mt){
      short8v A = ldA(sm + X30, mt*16, S_P, 0, wtid);
      f32x4 c0={0.f,0.f,0.f,0.f}, c1={0.f,0.f,0.f,0.f};
      f32x4 d0={0.f,0.f,0.f,0.f}, d1={0.f,0.f,0.f,0.f};
      c0 = MFMA(A,Bkh0,c0); c0 = MFMA(A,Bkl0,c0);
      c1 = MFMA(A,Bkh1,c1); c1 = MFMA(A,Bkl1,c1);
      d0 = MFMA(A,Bv0,d0);  d1 = MFMA(A,Bv1,d1);
      #pragma unroll
      for (int rg=0;rg<4;++rg){
        int row = mt*16 + quad*4 + rg;
        sm[KT + row*S_KT + m15] = f2b(c0[rg]);
        sm[VH + row*S_KT + m15] = f2b(d0[rg]);
        if (m15 < 14){
          sm[KT + row*S_KT + 16+m15] = f2b(c1[rg]);
          sm[VH + row*S_KT + 16+m15] = f2b(d1[rg]);
        }
      }
    }
    attn_phase<false>(sm, wtid, 0, nullptr, g_mha, b_mha);
    attn_phase<false>(sm, wtid, 1, nullptr, g_mha, b_mha);
    attn_phase<false>(sm, wtid, 2, nullptr, g_mha, b_mha);
  }

  // ---- stage 4: PFF30 -> x90 (KT/VH dead; X90 pads: head = finite VH leftovers x zero-B, tail zeroed) ----
  pff30<true>(sm, wtid, wf, b1, b2, g_pff, b_pff);
  // ---- stage 5: PFF90 (x90 in-place; H90 aliases H30) ----
  pff90(sm, wtid, wf, b1p, b2p, g_pff1, b_pff1);
  // ---- classifier + softmax ----
  classifier(sm, wtid, wf, bc1, Wc2, bc2, out, row0);
}

extern "C" void kernel_launch(void* const* d_in, const int* in_sizes, int n_in,
                              void* d_out, int out_size, void* d_ws, size_t ws_size,
                              hipStream_t stream)
{
  const float* q     = (const float*)d_in[0];
  const float* k     = (const float*)d_in[1];
  const float* v     = (const float*)d_in[2];
  const float* Wq    = (const float*)d_in[3];
  const float* Wk    = (const float*)d_in[4];
  const float* Wv    = (const float*)d_in[5];
  const float* g_mha = (const float*)d_in[6];
  const float* b_mha = (const float*)d_in[7];
  const float* W1    = (const float*)d_in[8];
  const float* b1    = (const float*)d_in[9];
  const float* W2    = (const float*)d_in[10];
  const float* b2    = (const float*)d_in[11];
  const float* g_pff = (const float*)d_in[12];
  const float* b_pff = (const float*)d_in[13];
  const float* W1p   = (const float*)d_in[14];
  const float* b1p   = (const float*)d_in[15];
  const float* W2p   = (const float*)d_in[16];
  const float* b2p   = (const float*)d_in[17];
  const float* g_pff1= (const float*)d_in[18];
  const float* b_pff1= (const float*)d_in[19];
  const float* Wc1   = (const float*)d_in[20];
  const float* bc1   = (const float*)d_in[21];
  const float* Wc2   = (const float*)d_in[22];
  const float* bc2   = (const float*)d_in[23];

  unsigned short* wf = (unsigned short*)d_ws;
  const int nrows = in_sizes[0] / 90;

  hipLaunchKernelGGL(prep_kernel, dim3((NFRAG*512 + 255)/256), dim3(256), 0, stream,
                     Wq, Wk, Wv, W1, W2, W1p, W2p, Wc1, wf);

  hipLaunchKernelGGL(moct_kernel, dim3(nrows/32), dim3(128), 0, stream,
    q, k, v, g_mha, b_mha, b1, b2, g_pff, b_pff,
    b1p, b2p, g_pff1, b_pff1, bc1, Wc2, bc2, wf, (float*)d_out);
}

// Round 5
// 240.474 us; speedup vs baseline: 1.2994x; 1.0202x over previous
//
#include <hip/hip_runtime.h>
#include <hip/hip_bf16.h>

#define EPS 1e-6f
#define INV_TEMP 0.31622776601683794f   // 1/sqrt(10), folded into M = Wq^T Wk / T

typedef float f32x4 __attribute__((ext_vector_type(4)));
typedef short short8v __attribute__((ext_vector_type(8)));
typedef unsigned uint4v __attribute__((ext_vector_type(4)));

#define MFMA(a,b,c) __builtin_amdgcn_mfma_f32_16x16x32_bf16(a,b,c,0,0,0)

// ---------- B-fragment table in d_ws (bf16 shorts), 55 frags x 512 shorts ----------
// f=0,1 : M_hi nt0,1 — block-diag(3) of bf16(M), M=Wq^T Wk/T, [32k x 32n]
// f=2,3 : M_lo nt0,1 — block-diag(3) of bf16(M - M_hi)   (hi/lo pair => fp32-accurate M)
// f=4,5 : Wv  nt0,1  — block-diag(3) of Wv
// f=6,7 : W1 nt0,1 (K=30,N=30)   f=8,9: W2 nt0,1
// f=10+kt*6+nt : W1p (K=90,N=90) f=28+kt*6+nt: W2p   f=46+kt*3+nt: Wc1 (K=90,N=45)
// prep zeroes all out-of-range K/N rows -> A-fragment k-pad contributes 0 if finite.
#define NFRAG 55

// ---------- per-wave LDS layout (offsets in shorts), WSM=4992 -> 8 blocks/CU ----------
// X30 [48][40] @0        : stages 1..4 (cols 30,31 zeroed once)
// KT  [48][30] @1920     : stages 1,3 (aliases H30; H30 dead then)
// H30 [48][32] @1920     : stages 2,4 transient (cols 30,31 rewritten as 0 each pass)
// H90 [16][96] @1920     : stage 5 (H30 dead)   C1T [16][48] @1920 : classifier
// VH  [48][30] @3456     : stages 1,3
// X90 [16][96] @3456     : stages 4..6 (aliases VH; pads cols 90..95 zeroed post-stage3)
#define X30   0
#define KT    1920
#define H30   1920
#define H90   1920
#define C1T   1920
#define VH    3456
#define X90   3456
#define WSM   4992     // shorts per wave = 9984 B -> 19968 B/block -> 8 blocks/CU

#define S_P   40       // X30 row stride (80 B, near-conflict-free b128)
#define S_H   32       // H30 row stride (64 B; 8-way b128 conflicts accepted -> LDS pipe)
#define S_X9  96       // X90/H90 row stride (192 B; conflicts accepted)
#define S_C1  48
#define S_KT  30       // KT/VH row stride (scalar dword access only)

// ---------------- bf16 conversion ----------------
__device__ __forceinline__ unsigned short f2b_sw(float x){       // RNE, host-prep use
  unsigned u = __float_as_uint(x);
  u += 0x7fffu + ((u>>16)&1u);
  return (unsigned short)(u>>16);
}
__device__ __forceinline__ unsigned pack2(float a, float b){     // low=a, high=b, RNE
  float2 t; t.x = a; t.y = b;
  __hip_bfloat162 h = __float22bfloat162_rn(t);
  unsigned u; __builtin_memcpy(&u, &h, 4); return u;
}
__device__ __forceinline__ unsigned short f2b(float x){
  __hip_bfloat16 h = __float2bfloat16(x);
  unsigned short u; __builtin_memcpy(&u, &h, 2); return u;
}
__device__ __forceinline__ float b2f(unsigned u16){              // low 16 bits -> f32
  return __uint_as_float(u16<<16);
}
__device__ __forceinline__ float b2lo(unsigned u){ return __uint_as_float(u<<16); }
__device__ __forceinline__ float b2hi(unsigned u){ return __uint_as_float(u & 0xffff0000u); }
__device__ __forceinline__ short8v ldB(const unsigned short* __restrict__ wf, int f, int wtid){
  return *(const short8v*)(wf + f*512 + wtid*8);                 // 16B/lane
}
__device__ __forceinline__ short8v ldA(const unsigned short* sm, int rowbase, int stride, int koff, int wtid){
  return *(const short8v*)(sm + (rowbase + (wtid&15))*stride + koff + (wtid>>4)*8);
}
__device__ __forceinline__ float qsum16(float v){                // sum across 16-lane quad
  v += __shfl_xor(v,1,64); v += __shfl_xor(v,2,64);
  v += __shfl_xor(v,4,64); v += __shfl_xor(v,8,64);
  return v;
}

// ---------------- prep: bake weights into B-fragment order ----------------
__global__ void prep_kernel(const float* __restrict__ Wq, const float* __restrict__ Wk,
                            const float* __restrict__ Wv, const float* __restrict__ W1,
                            const float* __restrict__ W2, const float* __restrict__ W1p,
                            const float* __restrict__ W2p, const float* __restrict__ Wc1,
                            unsigned short* __restrict__ wf)
{
  int t = blockIdx.x*blockDim.x + threadIdx.x;
  if (t >= NFRAG*512) return;
  int f = t>>9, e = t&511, lane = e>>3, j = e&7;
  int n = lane&15, kk = (lane>>4)*8 + j;
  float val = 0.f;
  if (f < 6){
    // block-diagonal attention operators, [32 k x 32 n]
    int ntb = (f<2) ? f : (f<4) ? (f-2) : (f-4);
    int gn = ntb*16 + n;          // n = t*10+d   (0..29 valid)
    int gk = kk;                  // k = t'*10+d' (0..29 valid)
    if (gn < 30 && gk < 30 && (gn/10) == (gk/10)){
      int dn = gn%10, dk = gk%10;
      if (f < 4){                 // M[dn,dk] = sum_e Wq[e,dn]*Wk[e,dk] / T
        float a = 0.f;
        for (int ee=0; ee<10; ++ee) a += Wq[ee*10+dn]*Wk[ee*10+dk];
        a *= INV_TEMP;
        float hi = b2f(f2b_sw(a));
        val = (f < 2) ? a : (a - hi);       // hi frag stores bf16(a); lo stores residual
      } else val = Wv[dn*10+dk];  // vh = v @ Wv^T
    }
  } else {
    const float* src; int K, N, kt, nt;
    if (f < 8)      { src = W1;  K=30; N=30; kt=0; nt=f-6; }
    else if (f < 10){ src = W2;  K=30; N=30; kt=0; nt=f-8; }
    else if (f < 28){ int g=f-10; src = W1p; K=90; N=90; kt=g/6; nt=g%6; }
    else if (f < 46){ int g=f-28; src = W2p; K=90; N=90; kt=g/6; nt=g%6; }
    else            { int g=f-46; src = Wc1; K=90; N=45; kt=g/3; nt=g%3; }
    int gn = nt*16 + n, gk = kt*32 + kk;
    if (gn < N && gk < K) val = src[gn*K + gk];   // B[k][n] = W[n][k]
  }
  wf[t] = f2b_sw(val);
}

// ---------------- per-branch attention (VALU, lanes 0..47 of the wave) ----------------
// query == residual (q slice in stage1, x30 in stage3); scores via fp32 qv . bf16 KT
template<bool S1>
__device__ __forceinline__ void attn_phase(unsigned short* sm, int wtid, int b,
    const float* res, const float* __restrict__ g, const float* __restrict__ bb)
{
  if (wtid >= 48) return;
  int r = wtid/3, s = wtid - 3*r;
  float qv[10], at[3];
  if (S1){
    #pragma unroll
    for (int d=0;d<10;++d) qv[d] = res[d];        // fp32 residual from registers
  } else {
    const unsigned* p = (const unsigned*)(sm + X30 + (b*16+r)*S_P + s*10);
    #pragma unroll
    for (int e=0;e<5;++e){ unsigned u=p[e]; qv[2*e]=b2lo(u); qv[2*e+1]=b2hi(u); }
  }
  const unsigned* kp = (const unsigned*)sm + (KT>>1) + (b*16+r)*15;
  #pragma unroll
  for (int t=0;t<3;++t){
    float a = 0.f;
    #pragma unroll
    for (int e=0;e<5;++e){ unsigned u = kp[t*5+e];
      a = fmaf(qv[2*e],   b2lo(u), a);
      a = fmaf(qv[2*e+1], b2hi(u), a); }
    at[t] = a;                                    // M already carries 1/sqrt(10)
  }
  float ov[10];
  #pragma unroll
  for (int d=0;d<10;++d) ov[d] = qv[d];           // residual
  const unsigned* vp = (const unsigned*)sm + (VH>>1) + (b*16+r)*15;
  #pragma unroll
  for (int t=0;t<3;++t){
    #pragma unroll
    for (int e=0;e<5;++e){ unsigned u = vp[t*5+e];
      ov[2*e]   = fmaf(at[t], b2lo(u), ov[2*e]);
      ov[2*e+1] = fmaf(at[t], b2hi(u), ov[2*e+1]); }
  }
  float sum=0.f, sq=0.f;
  #pragma unroll
  for (int d=0;d<10;++d){ sum += ov[d]; sq = fmaf(ov[d],ov[d],sq); }
  float mm = sum*0.1f, rs = rsqrtf(sq*0.1f - mm*mm + EPS);
  unsigned* wp = (unsigned*)(sm + X30 + (b*16+r)*S_P + s*10);
  #pragma unroll
  for (int e=0;e<5;++e){
    float z0 = fmaf((ov[2*e]-mm)*rs,   g[2*e],   bb[2*e]);
    float z1 = fmaf((ov[2*e+1]-mm)*rs, g[2*e+1], bb[2*e+1]);
    wp[e] = pack2(z0, z1);
  }
}

// ---------------- PFF30 on all 48 branch-rows ----------------
template<bool TO_X90>
__device__ __forceinline__ void pff30(unsigned short* sm, int wtid, const unsigned short* __restrict__ wf,
  const float* __restrict__ b1, const float* __restrict__ b2,
  const float* __restrict__ g, const float* __restrict__ bb)
{
  const int m15 = wtid & 15, quad = wtid >> 4;
  const bool c1ok = (m15 < 14);                 // col 16+m15 < 30
  float bi0 = b1[m15], bi1 = c1ok ? b1[16+m15] : 0.f;
  float b20 = b2[m15], b21 = c1ok ? b2[16+m15] : 0.f;
  float g0  = g[m15],  g1  = c1ok ? g[16+m15]  : 0.f;
  float e0  = bb[m15], e1  = c1ok ? bb[16+m15] : 0.f;
  short8v B10 = ldB(wf,6,wtid), B11 = ldB(wf,7,wtid), B20 = ldB(wf,8,wtid), B21 = ldB(wf,9,wtid);
  #pragma unroll 1
  for (int mt=0; mt<3; ++mt){
    short8v A = ldA(sm + X30, mt*16, S_P, 0, wtid);
    f32x4 C0 = {0.f,0.f,0.f,0.f}, C1 = {0.f,0.f,0.f,0.f};
    C0 = MFMA(A, B10, C0);
    C1 = MFMA(A, B11, C1);
    #pragma unroll
    for (int rg=0; rg<4; ++rg){
      int row = mt*16 + quad*4 + rg;
      sm[H30 + row*S_H + m15]    = f2b(fmaxf(C0[rg]+bi0, 0.f));
      sm[H30 + row*S_H + 16+m15] = f2b(fmaxf(C1[rg]+bi1, 0.f));  // cols 30,31 -> 0
    }
    short8v A2 = ldA(sm + H30, mt*16, S_H, 0, wtid);
    f32x4 D0 = {0.f,0.f,0.f,0.f}, D1 = {0.f,0.f,0.f,0.f};
    D0 = MFMA(A2, B20, D0);
    D1 = MFMA(A2, B21, D1);
    float y0[4], y1[4];
    #pragma unroll
    for (int rg=0; rg<4; ++rg){
      int row = mt*16 + quad*4 + rg;
      float r0 = b2f(sm[X30 + row*S_P + m15]);
      float r1 = c1ok ? b2f(sm[X30 + row*S_P + 16+m15]) : 0.f;
      y0[rg] = D0[rg] + b20 + r0;
      y1[rg] = c1ok ? (D1[rg] + b21 + r1) : 0.f;
    }
    #pragma unroll
    for (int rg=0; rg<4; ++rg){
      float sr = qsum16(y0[rg] + y1[rg]);
      float qr = qsum16(y0[rg]*y0[rg] + y1[rg]*y1[rg]);
      float mm = sr * (1.f/30.f);
      float rs = rsqrtf(qr*(1.f/30.f) - mm*mm + EPS);
      float z0 = fmaf((y0[rg]-mm)*rs, g0, e0);
      float z1 = fmaf((y1[rg]-mm)*rs, g1, e1);   // 0 when !c1ok
      if (!TO_X90){
        int row = mt*16 + quad*4 + rg;
        sm[X30 + row*S_P + m15]    = f2b(z0);
        sm[X30 + row*S_P + 16+m15] = f2b(z1);    // cols 30,31 stay 0
      } else {
        int rr = quad*4 + rg;                    // brow = mt*16+rr -> x90[rr][mt*30+col]
        sm[X90 + rr*S_X9 + mt*30 + m15]    = f2b(z0);
        sm[X90 + rr*S_X9 + mt*30 + 16+m15] = f2b(z1);
      }
    }
  }
}

// ---------------- PFF90 on x90 [16 x 90] ----------------
__device__ __forceinline__ void pff90(unsigned short* sm, int wtid, const unsigned short* __restrict__ wf,
  const float* __restrict__ b1p, const float* __restrict__ b2p,
  const float* __restrict__ g1, const float* __restrict__ bb1)
{
  const int m15 = wtid & 15, quad = wtid >> 4;
  short8v A0 = ldA(sm+X90, 0, S_X9, 0,  wtid);
  short8v A1 = ldA(sm+X90, 0, S_X9, 32, wtid);
  short8v A2 = ldA(sm+X90, 0, S_X9, 64, wtid);
  #pragma unroll
  for (int nt=0; nt<6; ++nt){
    f32x4 c = {0.f,0.f,0.f,0.f};
    c = MFMA(A0, ldB(wf, 10+nt, wtid), c);
    c = MFMA(A1, ldB(wf, 16+nt, wtid), c);
    c = MFMA(A2, ldB(wf, 22+nt, wtid), c);
    int col = nt*16 + m15;
    float bi = (col < 90) ? b1p[col] : 0.f;
    #pragma unroll
    for (int rg=0; rg<4; ++rg)
      sm[H90 + (quad*4+rg)*S_X9 + col] = f2b(fmaxf(c[rg]+bi, 0.f));  // cols>=90 -> 0
  }
  short8v H0 = ldA(sm+H90, 0, S_X9, 0,  wtid);
  short8v H1 = ldA(sm+H90, 0, S_X9, 32, wtid);
  short8v H2 = ldA(sm+H90, 0, S_X9, 64, wtid);
  float y[6][4];
  #pragma unroll
  for (int nt=0; nt<6; ++nt){
    f32x4 d = {0.f,0.f,0.f,0.f};
    d = MFMA(H0, ldB(wf, 28+nt, wtid), d);
    d = MFMA(H1, ldB(wf, 34+nt, wtid), d);
    d = MFMA(H2, ldB(wf, 40+nt, wtid), d);
    int col = nt*16 + m15;
    bool ok = (col < 90);
    float b2v = ok ? b2p[col] : 0.f;
    #pragma unroll
    for (int rg=0; rg<4; ++rg){
      float rv = ok ? b2f(sm[X90 + (quad*4+rg)*S_X9 + col]) : 0.f;
      y[nt][rg] = ok ? (d[rg] + b2v + rv) : 0.f;
    }
  }
  #pragma unroll
  for (int rg=0; rg<4; ++rg){
    float ps = 0.f, pq = 0.f;
    #pragma unroll
    for (int nt=0; nt<6; ++nt){ ps += y[nt][rg]; pq = fmaf(y[nt][rg], y[nt][rg], pq); }
    float sr = qsum16(ps), qr = qsum16(pq);
    float mm = sr*(1.f/90.f);
    float rs = rsqrtf(qr*(1.f/90.f) - mm*mm + EPS);
    int row = quad*4 + rg;
    #pragma unroll
    for (int nt=0; nt<6; ++nt){
      int col = nt*16 + m15;
      if (col < 90)
        sm[X90 + row*S_X9 + col] = f2b(fmaf((y[nt][rg]-mm)*rs, g1[col], bb1[col]));
    }
  }
}

// ---------------- classifier + softmax ----------------
__device__ __forceinline__ void classifier(unsigned short* sm, int wtid, const unsigned short* __restrict__ wf,
  const float* __restrict__ bc1, const float* __restrict__ Wc2, const float* __restrict__ bc2,
  float* __restrict__ out, int row0)
{
  const int m15 = wtid & 15, quad = wtid >> 4;
  short8v A0 = ldA(sm+X90, 0, S_X9, 0,  wtid);
  short8v A1 = ldA(sm+X90, 0, S_X9, 32, wtid);
  short8v A2 = ldA(sm+X90, 0, S_X9, 64, wtid);
  #pragma unroll
  for (int nt=0; nt<3; ++nt){
    f32x4 c = {0.f,0.f,0.f,0.f};
    c = MFMA(A0, ldB(wf, 46+nt, wtid), c);
    c = MFMA(A1, ldB(wf, 49+nt, wtid), c);
    c = MFMA(A2, ldB(wf, 52+nt, wtid), c);
    int col = nt*16 + m15;
    float bi = (col < 45) ? bc1[col] : 0.f;
    #pragma unroll
    for (int rg=0; rg<4; ++rg)
      sm[C1T + (quad*4+rg)*S_C1 + col] = f2b(fmaxf(c[rg]+bi, 0.f));
  }
  int row = m15, p = quad;
  int i0 = p*12, cnt = (p<3) ? 12 : 9;
  float lg0=0.f, lg1=0.f, lg2=0.f;
  for (int ii=0; ii<cnt; ++ii){
    float cv = b2f(sm[C1T + row*S_C1 + i0+ii]);
    lg0 = fmaf(cv, Wc2[     i0+ii], lg0);
    lg1 = fmaf(cv, Wc2[45 + i0+ii], lg1);
    lg2 = fmaf(cv, Wc2[90 + i0+ii], lg2);
  }
  lg0 += __shfl_xor(lg0,16,64); lg0 += __shfl_xor(lg0,32,64);
  lg1 += __shfl_xor(lg1,16,64); lg1 += __shfl_xor(lg1,32,64);
  lg2 += __shfl_xor(lg2,16,64); lg2 += __shfl_xor(lg2,32,64);
  lg0 += bc2[0]; lg1 += bc2[1]; lg2 += bc2[2];
  float mx = fmaxf(lg0, fmaxf(lg1,lg2));
  float x0 = __expf(lg0-mx), x1 = __expf(lg1-mx), x2 = __expf(lg2-mx);
  float inv = 1.f/(x0+x1+x2);
  if (p == 0){
    float* o = out + (size_t)(row0+row)*3;
    o[0]=x0*inv; o[1]=x1*inv; o[2]=x2*inv;
  }
}

// ---------------- main: 128 threads = 2 independent waves, 16 rows each ----------------
__global__ __launch_bounds__(128, 4) void moct_kernel(
  const float* __restrict__ q, const float* __restrict__ k, const float* __restrict__ v,
  const float* __restrict__ g_mha, const float* __restrict__ b_mha,
  const float* __restrict__ b1, const float* __restrict__ b2,
  const float* __restrict__ g_pff, const float* __restrict__ b_pff,
  const float* __restrict__ b1p, const float* __restrict__ b2p,
  const float* __restrict__ g_pff1, const float* __restrict__ b_pff1,
  const float* __restrict__ bc1, const float* __restrict__ Wc2, const float* __restrict__ bc2,
  const unsigned short* __restrict__ wf,
  float* __restrict__ out)
{
  __shared__ __align__(16) unsigned short smem[2*WSM];
  const int tid = threadIdx.x, wv = tid>>6, wtid = tid&63;
  unsigned short* sm = smem + wv*WSM;
  const int m15 = wtid & 15, quad = wtid >> 4;
  const int row0 = blockIdx.x*32 + wv*16;

  // X30 k-pad (shorts 30,31 of each of 48 rows) = 0 once; never overwritten after.
  if (wtid < 48) *(unsigned*)(sm + X30 + wtid*S_P + 30) = 0u;

  // ---- stage 1: project k,v with block-diag B (single batched load phase) ----
  {
    const float* kbase = k + (size_t)(row0+m15)*90;
    const float* vbase = v + (size_t)(row0+m15)*90;
    uint4v uk[3], uv[3];
    #pragma unroll
    for (int b=0;b<3;++b){
      const float2* kp = (const float2*)(kbase + b*30 + quad*8);
      const float2* vp = (const float2*)(vbase + b*30 + quad*8);
      float2 k0=kp[0], k1=kp[1], k2=kp[2];
      float2 v0=vp[0], v1=vp[1], v2=vp[2];
      float2 k3, v3;
      if (b==2 && quad==3){ k3=make_float2(0.f,0.f); v3=make_float2(0.f,0.f); } // k=30,31 pad; avoids OOB on last row
      else                { k3=kp[3]; v3=vp[3]; }
      uk[b][0]=pack2(k0.x,k0.y); uk[b][1]=pack2(k1.x,k1.y);
      uk[b][2]=pack2(k2.x,k2.y); uk[b][3]=pack2(k3.x,k3.y);
      uv[b][0]=pack2(v0.x,v0.y); uv[b][1]=pack2(v1.x,v1.y);
      uv[b][2]=pack2(v2.x,v2.y); uv[b][3]=pack2(v3.x,v3.y);
    }
    float res[3][10];
    if (wtid < 48){
      int r = wtid/3, s = wtid - 3*r;
      #pragma unroll
      for (int b=0;b<3;++b){
        const float2* rp = (const float2*)(q + (size_t)(row0+r)*90 + b*30 + s*10);
        #pragma unroll
        for (int e=0;e<5;++e){ float2 t2=rp[e]; res[b][2*e]=t2.x; res[b][2*e+1]=t2.y; }
      }
    }
    short8v Bkh0=ldB(wf,0,wtid), Bkh1=ldB(wf,1,wtid);
    short8v Bkl0=ldB(wf,2,wtid), Bkl1=ldB(wf,3,wtid);
    short8v Bv0 =ldB(wf,4,wtid), Bv1 =ldB(wf,5,wtid);
    #pragma unroll
    for (int b=0;b<3;++b){
      short8v A;
      __builtin_memcpy(&A,&uk[b],16);
      f32x4 c0={0.f,0.f,0.f,0.f}, c1={0.f,0.f,0.f,0.f};
      c0 = MFMA(A,Bkh0,c0); c0 = MFMA(A,Bkl0,c0);
      c1 = MFMA(A,Bkh1,c1); c1 = MFMA(A,Bkl1,c1);
      #pragma unroll
      for (int rg=0;rg<4;++rg){
        int row = b*16 + quad*4 + rg;
        sm[KT + row*S_KT + m15] = f2b(c0[rg]);
        if (m15 < 14) sm[KT + row*S_KT + 16+m15] = f2b(c1[rg]);
      }
      __builtin_memcpy(&A,&uv[b],16);
      f32x4 d0={0.f,0.f,0.f,0.f}, d1={0.f,0.f,0.f,0.f};
      d0 = MFMA(A,Bv0,d0); d1 = MFMA(A,Bv1,d1);
      #pragma unroll
      for (int rg=0;rg<4;++rg){
        int row = b*16 + quad*4 + rg;
        sm[VH + row*S_KT + m15] = f2b(d0[rg]);
        if (m15 < 14) sm[VH + row*S_KT + 16+m15] = f2b(d1[rg]);
      }
    }
    attn_phase<true>(sm, wtid, 0, res[0], g_mha, b_mha);
    attn_phase<true>(sm, wtid, 1, res[1], g_mha, b_mha);
    attn_phase<true>(sm, wtid, 2, res[2], g_mha, b_mha);
  }

  // ---- stage 2: PFF30 (in-place x30; H30 clobbers KT — stage 3 recomputes it) ----
  pff30<false>(sm, wtid, wf, b1, b2, g_pff, b_pff);

  // ---- stage 3: MHA(x,x,x); A straight from X30, no repack ----
  {
    short8v Bkh0=ldB(wf,0,wtid), Bkh1=ldB(wf,1,wtid);
    short8v Bkl0=ldB(wf,2,wtid), Bkl1=ldB(wf,3,wtid);
    short8v Bv0 =ldB(wf,4,wtid), Bv1 =ldB(wf,5,wtid);
    #pragma unroll
    for (int mt=0; mt<3; ++mt){
      short8v A = ldA(sm + X30, mt*16, S_P, 0, wtid);
      f32x4 c0={0.f,0.f,0.f,0.f}, c1={0.f,0.f,0.f,0.f};
      f32x4 d0={0.f,0.f,0.f,0.f}, d1={0.f,0.f,0.f,0.f};
      c0 = MFMA(A,Bkh0,c0); c0 = MFMA(A,Bkl0,c0);
      c1 = MFMA(A,Bkh1,c1); c1 = MFMA(A,Bkl1,c1);
      d0 = MFMA(A,Bv0,d0);  d1 = MFMA(A,Bv1,d1);
      #pragma unroll
      for (int rg=0;rg<4;++rg){
        int row = mt*16 + quad*4 + rg;
        sm[KT + row*S_KT + m15] = f2b(c0[rg]);
        sm[VH + row*S_KT + m15] = f2b(d0[rg]);
        if (m15 < 14){
          sm[KT + row*S_KT + 16+m15] = f2b(c1[rg]);
          sm[VH + row*S_KT + 16+m15] = f2b(d1[rg]);
        }
      }
    }
    attn_phase<false>(sm, wtid, 0, nullptr, g_mha, b_mha);
    attn_phase<false>(sm, wtid, 1, nullptr, g_mha, b_mha);
    attn_phase<false>(sm, wtid, 2, nullptr, g_mha, b_mha);
  }

  // X90 k-pad cols 90..95 of all 16 rows = 0 (region aliased VH until now).
  if (wtid < 48){
    int row = wtid/3, j = wtid - 3*row;
    ((unsigned*)sm)[(X90>>1) + row*(S_X9>>1) + 45 + j] = 0u;
  }

  // ---- stage 4: PFF30 -> x90 (KT/VH dead; X90 pads zeroed above) ----
  pff30<true>(sm, wtid, wf, b1, b2, g_pff, b_pff);
  // ---- stage 5: PFF90 (x90 in-place; H90 aliases H30) ----
  pff90(sm, wtid, wf, b1p, b2p, g_pff1, b_pff1);
  // ---- classifier + softmax ----
  classifier(sm, wtid, wf, bc1, Wc2, bc2, out, row0);
}

extern "C" void kernel_launch(void* const* d_in, const int* in_sizes, int n_in,
                              void* d_out, int out_size, void* d_ws, size_t ws_size,
                              hipStream_t stream)
{
  const float* q     = (const float*)d_in[0];
  const float* k     = (const float*)d_in[1];
  const float* v     = (const float*)d_in[2];
  const float* Wq    = (const float*)d_in[3];
  const float* Wk    = (const float*)d_in[4];
  const float* Wv    = (const float*)d_in[5];
  const float* g_mha = (const float*)d_in[6];
  const float* b_mha = (const float*)d_in[7];
  const float* W1    = (const float*)d_in[8];
  const float* b1    = (const float*)d_in[9];
  const float* W2    = (const float*)d_in[10];
  const float* b2    = (const float*)d_in[11];
  const float* g_pff = (const float*)d_in[12];
  const float* b_pff = (const float*)d_in[13];
  const float* W1p   = (const float*)d_in[14];
  const float* b1p   = (const float*)d_in[15];
  const float* W2p   = (const float*)d_in[16];
  const float* b2p   = (const float*)d_in[17];
  const float* g_pff1= (const float*)d_in[18];
  const float* b_pff1= (const float*)d_in[19];
  const float* Wc1   = (const float*)d_in[20];
  const float* bc1   = (const float*)d_in[21];
  const float* Wc2   = (const float*)d_in[22];
  const float* bc2   = (const float*)d_in[23];

  unsigned short* wf = (unsigned short*)d_ws;
  const int nrows = in_sizes[0] / 90;

  hipLaunchKernelGGL(prep_kernel, dim3((NFRAG*512 + 255)/256), dim3(256), 0, stream,
                     Wq, Wk, Wv, W1, W2, W1p, W2p, Wc1, wf);

  hipLaunchKernelGGL(moct_kernel, dim3(nrows/32), dim3(128), 0, stream,
    q, k, v, g_mha, b_mha, b1, b2, g_pff, b_pff,
    b1p, b2p, g_pff1, b_pff1, bc1, Wc2, bc2, wf, (float*)d_out);
}

// Round 7
// 239.140 us; speedup vs baseline: 1.3067x; 1.0056x over previous
//
#include <hip/hip_runtime.h>
#include <hip/hip_bf16.h>

#define EPS 1e-6f
#define INV_TEMP 0.31622776601683794f   // 1/sqrt(10), folded into M = Wq^T Wk / T

typedef float f32x4 __attribute__((ext_vector_type(4)));
typedef short short8v __attribute__((ext_vector_type(8)));
typedef unsigned uint4v __attribute__((ext_vector_type(4)));

#define MFMA(a,b,c) __builtin_amdgcn_mfma_f32_16x16x32_bf16(a,b,c,0,0,0)

// ---------- B-fragment table in d_ws (bf16 shorts), 55 frags x 512 shorts ----------
// f=0,1 : M_hi nt0,1 — block-diag(3) of bf16(M), M=Wq^T Wk/T, [32k x 32n]
// f=2,3 : M_lo nt0,1 — block-diag(3) of bf16(M - M_hi)   (hi/lo pair => fp32-accurate M)
// f=4,5 : Wv  nt0,1  — block-diag(3) of Wv
// f=6,7 : W1 nt0,1 (K=30,N=30)   f=8,9: W2 nt0,1
// f=10+kt*6+nt : W1p (K=90,N=90) f=28+kt*6+nt: W2p   f=46+kt*3+nt: Wc1 (K=90,N=45)
// prep zeroes all out-of-range K/N rows -> A-fragment k-pad contributes 0 if finite.
#define NFRAG 55

// ---------- per-wave LDS layout (offsets in shorts), WSM=5120 -> 8 blocks/CU ----------
// region1 @0    [1920]: X30 [48][40] stages 1..4   | H90 [16][104] stage 5 (X30 dead)
// region2 @1920 [1536]: KT [48][30] stages 1,3 | H30 [48][32, unit-swizzled] 2,4 | C1T [16][48]
// region3 @3456 [1664]: VH [48][30] stages 1,3 | X90 [16][104] stages 4..6
#define X30   0
#define H90   0
#define KT    1920
#define H30   1920
#define C1T   1920
#define VH    3456
#define X90   3456
#define WSM   5120     // shorts per wave = 10240 B -> 20480 B/block -> 8 blocks/CU exactly

#define S_P   40       // X30 row stride (80 B rows: 2-way on b128, free)
#define S_H   32       // H30 row stride (64 B; XOR-swizzled units -> 2-way, free)
#define S_X9  104      // X90/H90 row stride (208 B rows: 2-way on b128, free)
#define S_C1  48
#define S_KT  30       // KT/VH row stride (scalar dword access, 16-row period conflict-free)

// ---------------- bf16 conversion ----------------
__device__ __forceinline__ unsigned short f2b_sw(float x){       // RNE, host-prep use
  unsigned u = __float_as_uint(x);
  u += 0x7fffu + ((u>>16)&1u);
  return (unsigned short)(u>>16);
}
__device__ __forceinline__ unsigned pack2(float a, float b){     // low=a, high=b, RNE
  float2 t; t.x = a; t.y = b;
  __hip_bfloat162 h = __float22bfloat162_rn(t);
  unsigned u; __builtin_memcpy(&u, &h, 4); return u;
}
__device__ __forceinline__ unsigned short f2b(float x){
  __hip_bfloat16 h = __float2bfloat16(x);
  unsigned short u; __builtin_memcpy(&u, &h, 2); return u;
}
__device__ __forceinline__ float b2f(unsigned u16){              // low 16 bits -> f32
  return __uint_as_float(u16<<16);
}
__device__ __forceinline__ float b2lo(unsigned u){ return __uint_as_float(u<<16); }
__device__ __forceinline__ float b2hi(unsigned u){ return __uint_as_float(u & 0xffff0000u); }
__device__ __forceinline__ short8v ldB(const unsigned short* __restrict__ wf, int f, int wtid){
  return *(const short8v*)(wf + f*512 + wtid*8);                 // 16B/lane
}
__device__ __forceinline__ short8v ldA(const unsigned short* sm, int rowbase, int stride, int koff, int wtid){
  return *(const short8v*)(sm + (rowbase + (wtid&15))*stride + koff + (wtid>>4)*8);
}
__device__ __forceinline__ float qsum16(float v){                // sum across 16-lane quad
  v += __shfl_xor(v,1,64); v += __shfl_xor(v,2,64);
  v += __shfl_xor(v,4,64); v += __shfl_xor(v,8,64);
  return v;
}

// ---------------- prep: bake weights into B-fragment order ----------------
__global__ void prep_kernel(const float* __restrict__ Wq, const float* __restrict__ Wk,
                            const float* __restrict__ Wv, const float* __restrict__ W1,
                            const float* __restrict__ W2, const float* __restrict__ W1p,
                            const float* __restrict__ W2p, const float* __restrict__ Wc1,
                            unsigned short* __restrict__ wf)
{
  int t = blockIdx.x*blockDim.x + threadIdx.x;
  if (t >= NFRAG*512) return;
  int f = t>>9, e = t&511, lane = e>>3, j = e&7;
  int n = lane&15, kk = (lane>>4)*8 + j;
  float val = 0.f;
  if (f < 6){
    // block-diagonal attention operators, [32 k x 32 n]
    int ntb = (f<2) ? f : (f<4) ? (f-2) : (f-4);
    int gn = ntb*16 + n;          // n = t*10+d   (0..29 valid)
    int gk = kk;                  // k = t'*10+d' (0..29 valid)
    if (gn < 30 && gk < 30 && (gn/10) == (gk/10)){
      int dn = gn%10, dk = gk%10;
      if (f < 4){                 // M[dn,dk] = sum_e Wq[e,dn]*Wk[e,dk] / T
        float a = 0.f;
        for (int ee=0; ee<10; ++ee) a += Wq[ee*10+dn]*Wk[ee*10+dk];
        a *= INV_TEMP;
        float hi = b2f(f2b_sw(a));
        val = (f < 2) ? a : (a - hi);       // hi frag stores bf16(a); lo stores residual
      } else val = Wv[dn*10+dk];  // vh = v @ Wv^T
    }
  } else {
    const float* src; int K, N, kt, nt;
    if (f < 8)      { src = W1;  K=30; N=30; kt=0; nt=f-6; }
    else if (f < 10){ src = W2;  K=30; N=30; kt=0; nt=f-8; }
    else if (f < 28){ int g=f-10; src = W1p; K=90; N=90; kt=g/6; nt=g%6; }
    else if (f < 46){ int g=f-28; src = W2p; K=90; N=90; kt=g/6; nt=g%6; }
    else            { int g=f-46; src = Wc1; K=90; N=45; kt=g/3; nt=g%3; }
    int gn = nt*16 + n, gk = kt*32 + kk;
    if (gn < N && gk < K) val = src[gn*K + gk];   // B[k][n] = W[n][k]
  }
  wf[t] = f2b_sw(val);
}

// ---------------- per-branch attention (VALU, lanes 0..47 of the wave) ----------------
// query == residual (q slice in stage1, x30 in stage3); scores via fp32 qv . bf16 KT
template<bool S1>
__device__ __forceinline__ void attn_phase(unsigned short* sm, int wtid, int b,
    const float* res, const float* __restrict__ g, const float* __restrict__ bb)
{
  if (wtid >= 48) return;
  int r = wtid/3, s = wtid - 3*r;
  float qv[10], at[3];
  if (S1){
    #pragma unroll
    for (int d=0;d<10;++d) qv[d] = res[d];        // fp32 residual from registers
  } else {
    const unsigned* p = (const unsigned*)(sm + X30 + (b*16+r)*S_P + s*10);
    #pragma unroll
    for (int e=0;e<5;++e){ unsigned u=p[e]; qv[2*e]=b2lo(u); qv[2*e+1]=b2hi(u); }
  }
  const unsigned* kp = (const unsigned*)sm + (KT>>1) + (b*16+r)*15;
  #pragma unroll
  for (int t=0;t<3;++t){
    float a = 0.f;
    #pragma unroll
    for (int e=0;e<5;++e){ unsigned u = kp[t*5+e];
      a = fmaf(qv[2*e],   b2lo(u), a);
      a = fmaf(qv[2*e+1], b2hi(u), a); }
    at[t] = a;                                    // M already carries 1/sqrt(10)
  }
  float ov[10];
  #pragma unroll
  for (int d=0;d<10;++d) ov[d] = qv[d];           // residual
  const unsigned* vp = (const unsigned*)sm + (VH>>1) + (b*16+r)*15;
  #pragma unroll
  for (int t=0;t<3;++t){
    #pragma unroll
    for (int e=0;e<5;++e){ unsigned u = vp[t*5+e];
      ov[2*e]   = fmaf(at[t], b2lo(u), ov[2*e]);
      ov[2*e+1] = fmaf(at[t], b2hi(u), ov[2*e+1]); }
  }
  float sum=0.f, sq=0.f;
  #pragma unroll
  for (int d=0;d<10;++d){ sum += ov[d]; sq = fmaf(ov[d],ov[d],sq); }
  float mm = sum*0.1f, rs = rsqrtf(sq*0.1f - mm*mm + EPS);
  unsigned* wp = (unsigned*)(sm + X30 + (b*16+r)*S_P + s*10);
  #pragma unroll
  for (int e=0;e<5;++e){
    float z0 = fmaf((ov[2*e]-mm)*rs,   g[2*e],   bb[2*e]);
    float z1 = fmaf((ov[2*e+1]-mm)*rs, g[2*e+1], bb[2*e+1]);
    wp[e] = pack2(z0, z1);
  }
}

// ---------------- PFF30 on all 48 branch-rows ----------------
// H30 is stored with 16B-unit XOR swizzle: logical unit u of row r lives at
// physical unit u ^ ((r>>1)&3)  -> ds_read_b128 spreads rows 0..7 over 8 banks.
template<bool TO_X90>
__device__ __forceinline__ void pff30(unsigned short* sm, int wtid, const unsigned short* __restrict__ wf,
  const float* __restrict__ b1, const float* __restrict__ b2,
  const float* __restrict__ g, const float* __restrict__ bb)
{
  const int m15 = wtid & 15, quad = wtid >> 4;
  const bool c1ok = (m15 < 14);                 // col 16+m15 < 30
  float bi0 = b1[m15], bi1 = c1ok ? b1[16+m15] : 0.f;
  float b20 = b2[m15], b21 = c1ok ? b2[16+m15] : 0.f;
  float g0  = g[m15],  g1  = c1ok ? g[16+m15]  : 0.f;
  float e0  = bb[m15], e1  = c1ok ? bb[16+m15] : 0.f;
  const int swr = (m15>>1)&3;                   // read-side swizzle (row = mt*16+m15)
  short8v B10 = ldB(wf,6,wtid), B11 = ldB(wf,7,wtid), B20 = ldB(wf,8,wtid), B21 = ldB(wf,9,wtid);
  #pragma unroll 1
  for (int mt=0; mt<3; ++mt){
    short8v A = ldA(sm + X30, mt*16, S_P, 0, wtid);
    f32x4 C0 = {0.f,0.f,0.f,0.f}, C1 = {0.f,0.f,0.f,0.f};
    C0 = MFMA(A, B10, C0);
    C1 = MFMA(A, B11, C1);
    #pragma unroll
    for (int rg=0; rg<4; ++rg){
      int row = mt*16 + quad*4 + rg;
      int swu = (row>>1)&3;                     // write-side swizzle
      int u0 = ((m15>>3) ^ swu) << 3;           // logical cols m15 (units 0,1)
      int u1 = ((2 + (m15>>3)) ^ swu) << 3;     // logical cols 16+m15 (units 2,3)
      sm[H30 + row*S_H + u0 + (m15&7)] = f2b(fmaxf(C0[rg]+bi0, 0.f));
      sm[H30 + row*S_H + u1 + (m15&7)] = f2b(fmaxf(C1[rg]+bi1, 0.f));  // cols 30,31 -> 0
    }
    short8v A2 = *(const short8v*)(sm + H30 + (mt*16 + m15)*S_H + ((quad ^ swr)<<3));
    f32x4 D0 = {0.f,0.f,0.f,0.f}, D1 = {0.f,0.f,0.f,0.f};
    D0 = MFMA(A2, B20, D0);
    D1 = MFMA(A2, B21, D1);
    float y0[4], y1[4];
    #pragma unroll
    for (int rg=0; rg<4; ++rg){
      int row = mt*16 + quad*4 + rg;
      float r0 = b2f(sm[X30 + row*S_P + m15]);
      float r1 = c1ok ? b2f(sm[X30 + row*S_P + 16+m15]) : 0.f;
      y0[rg] = D0[rg] + b20 + r0;
      y1[rg] = c1ok ? (D1[rg] + b21 + r1) : 0.f;
    }
    #pragma unroll
    for (int rg=0; rg<4; ++rg){
      float sr = qsum16(y0[rg] + y1[rg]);
      float qr = qsum16(y0[rg]*y0[rg] + y1[rg]*y1[rg]);
      float mm = sr * (1.f/30.f);
      float rs = rsqrtf(qr*(1.f/30.f) - mm*mm + EPS);
      float z0 = fmaf((y0[rg]-mm)*rs, g0, e0);
      float z1 = fmaf((y1[rg]-mm)*rs, g1, e1);   // 0 when !c1ok
      if (!TO_X90){
        int row = mt*16 + quad*4 + rg;
        sm[X30 + row*S_P + m15]    = f2b(z0);
        sm[X30 + row*S_P + 16+m15] = f2b(z1);    // cols 30,31 stay 0
      } else {
        int rr = quad*4 + rg;                    // brow = mt*16+rr -> x90[rr][mt*30+col]
        sm[X90 + rr*S_X9 + mt*30 + m15]    = f2b(z0);
        sm[X90 + rr*S_X9 + mt*30 + 16+m15] = f2b(z1);
      }
    }
  }
}

// ---------------- PFF90 on x90 [16 x 90] ----------------
__device__ __forceinline__ void pff90(unsigned short* sm, int wtid, const unsigned short* __restrict__ wf,
  const float* __restrict__ b1p, const float* __restrict__ b2p,
  const float* __restrict__ g1, const float* __restrict__ bb1)
{
  const int m15 = wtid & 15, quad = wtid >> 4;
  short8v A0 = ldA(sm+X90, 0, S_X9, 0,  wtid);
  short8v A1 = ldA(sm+X90, 0, S_X9, 32, wtid);
  short8v A2 = ldA(sm+X90, 0, S_X9, 64, wtid);
  #pragma unroll
  for (int nt=0; nt<6; ++nt){
    f32x4 c = {0.f,0.f,0.f,0.f};
    c = MFMA(A0, ldB(wf, 10+nt, wtid), c);
    c = MFMA(A1, ldB(wf, 16+nt, wtid), c);
    c = MFMA(A2, ldB(wf, 22+nt, wtid), c);
    int col = nt*16 + m15;
    float bi = (col < 90) ? b1p[col] : 0.f;
    #pragma unroll
    for (int rg=0; rg<4; ++rg)
      sm[H90 + (quad*4+rg)*S_X9 + col] = f2b(fmaxf(c[rg]+bi, 0.f));  // cols>=90 -> 0
  }
  short8v H0 = ldA(sm+H90, 0, S_X9, 0,  wtid);
  short8v H1 = ldA(sm+H90, 0, S_X9, 32, wtid);
  short8v H2 = ldA(sm+H90, 0, S_X9, 64, wtid);
  float y[6][4];
  #pragma unroll
  for (int nt=0; nt<6; ++nt){
    f32x4 d = {0.f,0.f,0.f,0.f};
    d = MFMA(H0, ldB(wf, 28+nt, wtid), d);
    d = MFMA(H1, ldB(wf, 34+nt, wtid), d);
    d = MFMA(H2, ldB(wf, 40+nt, wtid), d);
    int col = nt*16 + m15;
    bool ok = (col < 90);
    float b2v = ok ? b2p[col] : 0.f;
    #pragma unroll
    for (int rg=0; rg<4; ++rg){
      float rv = ok ? b2f(sm[X90 + (quad*4+rg)*S_X9 + col]) : 0.f;
      y[nt][rg] = ok ? (d[rg] + b2v + rv) : 0.f;
    }
  }
  #pragma unroll
  for (int rg=0; rg<4; ++rg){
    float ps = 0.f, pq = 0.f;
    #pragma unroll
    for (int nt=0; nt<6; ++nt){ ps += y[nt][rg]; pq = fmaf(y[nt][rg], y[nt][rg], pq); }
    float sr = qsum16(ps), qr = qsum16(pq);
    float mm = sr*(1.f/90.f);
    float rs = rsqrtf(qr*(1.f/90.f) - mm*mm + EPS);
    int row = quad*4 + rg;
    #pragma unroll
    for (int nt=0; nt<6; ++nt){
      int col = nt*16 + m15;
      if (col < 90)
        sm[X90 + row*S_X9 + col] = f2b(fmaf((y[nt][rg]-mm)*rs, g1[col], bb1[col]));
    }
  }
}

// ---------------- classifier + softmax ----------------
__device__ __forceinline__ void classifier(unsigned short* sm, int wtid, const unsigned short* __restrict__ wf,
  const float* __restrict__ bc1, const float* __restrict__ Wc2, const float* __restrict__ bc2,
  float* __restrict__ out, int row0)
{
  const int m15 = wtid & 15, quad = wtid >> 4;
  short8v A0 = ldA(sm+X90, 0, S_X9, 0,  wtid);
  short8v A1 = ldA(sm+X90, 0, S_X9, 32, wtid);
  short8v A2 = ldA(sm+X90, 0, S_X9, 64, wtid);
  #pragma unroll
  for (int nt=0; nt<3; ++nt){
    f32x4 c = {0.f,0.f,0.f,0.f};
    c = MFMA(A0, ldB(wf, 46+nt, wtid), c);
    c = MFMA(A1, ldB(wf, 49+nt, wtid), c);
    c = MFMA(A2, ldB(wf, 52+nt, wtid), c);
    int col = nt*16 + m15;
    float bi = (col < 45) ? bc1[col] : 0.f;
    #pragma unroll
    for (int rg=0; rg<4; ++rg)
      sm[C1T + (quad*4+rg)*S_C1 + col] = f2b(fmaxf(c[rg]+bi, 0.f));
  }
  int row = m15, p = quad;
  int i0 = p*12, cnt = (p<3) ? 12 : 9;
  float lg0=0.f, lg1=0.f, lg2=0.f;
  for (int ii=0; ii<cnt; ++ii){
    float cv = b2f(sm[C1T + row*S_C1 + i0+ii]);
    lg0 = fmaf(cv, Wc2[     i0+ii], lg0);
    lg1 = fmaf(cv, Wc2[45 + i0+ii], lg1);
    lg2 = fmaf(cv, Wc2[90 + i0+ii], lg2);
  }
  lg0 += __shfl_xor(lg0,16,64); lg0 += __shfl_xor(lg0,32,64);
  lg1 += __shfl_xor(lg1,16,64); lg1 += __shfl_xor(lg1,32,64);
  lg2 += __shfl_xor(lg2,16,64); lg2 += __shfl_xor(lg2,32,64);
  lg0 += bc2[0]; lg1 += bc2[1]; lg2 += bc2[2];
  float mx = fmaxf(lg0, fmaxf(lg1,lg2));
  float x0 = __expf(lg0-mx), x1 = __expf(lg1-mx), x2 = __expf(lg2-mx);
  float inv = 1.f/(x0+x1+x2);
  if (p == 0){
    float* o = out + (size_t)(row0+row)*3;
    o[0]=x0*inv; o[1]=x1*inv; o[2]=x2*inv;
  }
}

// ---------------- main: 128 threads = 2 independent waves, 16 rows each ----------------
__global__ __launch_bounds__(128, 4) void moct_kernel(
  const float* __restrict__ q, const float* __restrict__ k, const float* __restrict__ v,
  const float* __restrict__ g_mha, const float* __restrict__ b_mha,
  const float* __restrict__ b1, const float* __restrict__ b2,
  const float* __restrict__ g_pff, const float* __restrict__ b_pff,
  const float* __restrict__ b1p, const float* __restrict__ b2p,
  const float* __restrict__ g_pff1, const float* __restrict__ b_pff1,
  const float* __restrict__ bc1, const float* __restrict__ Wc2, const float* __restrict__ bc2,
  const unsigned short* __restrict__ wf,
  float* __restrict__ out)
{
  __shared__ __align__(16) unsigned short smem[2*WSM];
  const int tid = threadIdx.x, wv = tid>>6, wtid = tid&63;
  unsigned short* sm = smem + wv*WSM;
  const int m15 = wtid & 15, quad = wtid >> 4;
  const int row0 = blockIdx.x*32 + wv*16;

  // X30 k-pad (shorts 30,31 of each of 48 rows) = 0 once; never overwritten after.
  if (wtid < 48) *(unsigned*)(sm + X30 + wtid*S_P + 30) = 0u;

  // ---- stage 1: project k,v with block-diag B (single batched load phase) ----
  {
    const float* kbase = k + (size_t)(row0+m15)*90;
    const float* vbase = v + (size_t)(row0+m15)*90;
    uint4v uk[3], uv[3];
    #pragma unroll
    for (int b=0;b<3;++b){
      const float2* kp = (const float2*)(kbase + b*30 + quad*8);
      const float2* vp = (const float2*)(vbase + b*30 + quad*8);
      float2 k0=kp[0], k1=kp[1], k2=kp[2];
      float2 v0=vp[0], v1=vp[1], v2=vp[2];
      float2 k3, v3;
      if (b==2 && quad==3){ k3=make_float2(0.f,0.f); v3=make_float2(0.f,0.f); } // k=30,31 pad; avoids OOB on last row
      else                { k3=kp[3]; v3=vp[3]; }
      uk[b][0]=pack2(k0.x,k0.y); uk[b][1]=pack2(k1.x,k1.y);
      uk[b][2]=pack2(k2.x,k2.y); uk[b][3]=pack2(k3.x,k3.y);
      uv[b][0]=pack2(v0.x,v0.y); uv[b][1]=pack2(v1.x,v1.y);
      uv[b][2]=pack2(v2.x,v2.y); uv[b][3]=pack2(v3.x,v3.y);
    }
    float res[3][10];
    if (wtid < 48){
      int r = wtid/3, s = wtid - 3*r;
      #pragma unroll
      for (int b=0;b<3;++b){
        const float2* rp = (const float2*)(q + (size_t)(row0+r)*90 + b*30 + s*10);
        #pragma unroll
        for (int e=0;e<5;++e){ float2 t2=rp[e]; res[b][2*e]=t2.x; res[b][2*e+1]=t2.y; }
      }
    }
    short8v Bkh0=ldB(wf,0,wtid), Bkh1=ldB(wf,1,wtid);
    short8v Bkl0=ldB(wf,2,wtid), Bkl1=ldB(wf,3,wtid);
    short8v Bv0 =ldB(wf,4,wtid), Bv1 =ldB(wf,5,wtid);
    #pragma unroll
    for (int b=0;b<3;++b){
      short8v A;
      __builtin_memcpy(&A,&uk[b],16);
      f32x4 c0={0.f,0.f,0.f,0.f}, c1={0.f,0.f,0.f,0.f};
      c0 = MFMA(A,Bkh0,c0); c0 = MFMA(A,Bkl0,c0);
      c1 = MFMA(A,Bkh1,c1); c1 = MFMA(A,Bkl1,c1);
      #pragma unroll
      for (int rg=0;rg<4;++rg){
        int row = b*16 + quad*4 + rg;
        sm[KT + row*S_KT + m15] = f2b(c0[rg]);
        if (m15 < 14) sm[KT + row*S_KT + 16+m15] = f2b(c1[rg]);
      }
      __builtin_memcpy(&A,&uv[b],16);
      f32x4 d0={0.f,0.f,0.f,0.f}, d1={0.f,0.f,0.f,0.f};
      d0 = MFMA(A,Bv0,d0); d1 = MFMA(A,Bv1,d1);
      #pragma unroll
      for (int rg=0;rg<4;++rg){
        int row = b*16 + quad*4 + rg;
        sm[VH + row*S_KT + m15] = f2b(d0[rg]);
        if (m15 < 14) sm[VH + row*S_KT + 16+m15] = f2b(d1[rg]);
      }
    }
    attn_phase<true>(sm, wtid, 0, res[0], g_mha, b_mha);
    attn_phase<true>(sm, wtid, 1, res[1], g_mha, b_mha);
    attn_phase<true>(sm, wtid, 2, res[2], g_mha, b_mha);
  }

  // ---- stage 2: PFF30 (in-place x30; H30 clobbers KT — stage 3 recomputes it) ----
  pff30<false>(sm, wtid, wf, b1, b2, g_pff, b_pff);

  // ---- stage 3: MHA(x,x,x); A straight from X30, no repack ----
  {
    short8v Bkh0=ldB(wf,0,wtid), Bkh1=ldB(wf,1,wtid);
    short8v Bkl0=ldB(wf,2,wtid), Bkl1=ldB(wf,3,wtid);
    short8v Bv0 =ldB(wf,4,wtid), Bv1 =ldB(wf,5,wtid);
    #pragma unroll
    for (int mt=0; mt<3; ++mt){
      short8v A = ldA(sm + X30, mt*16, S_P, 0, wtid);
      f32x4 c0={0.f,0.f,0.f,0.f}, c1={0.f,0.f,0.f,0.f};
      f32x4 d0={0.f,0.f,0.f,0.f}, d1={0.f,0.f,0.f,0.f};
      c0 = MFMA(A,Bkh0,c0); c0 = MFMA(A,Bkl0,c0);
      c1 = MFMA(A,Bkh1,c1); c1 = MFMA(A,Bkl1,c1);
      d0 = MFMA(A,Bv0,d0);  d1 = MFMA(A,Bv1,d1);
      #pragma unroll
      for (int rg=0;rg<4;++rg){
        int row = mt*16 + quad*4 + rg;
        sm[KT + row*S_KT + m15] = f2b(c0[rg]);
        sm[VH + row*S_KT + m15] = f2b(d0[rg]);
        if (m15 < 14){
          sm[KT + row*S_KT + 16+m15] = f2b(c1[rg]);
          sm[VH + row*S_KT + 16+m15] = f2b(d1[rg]);
        }
      }
    }
    attn_phase<false>(sm, wtid, 0, nullptr, g_mha, b_mha);
    attn_phase<false>(sm, wtid, 1, nullptr, g_mha, b_mha);
    attn_phase<false>(sm, wtid, 2, nullptr, g_mha, b_mha);
  }

  // X90 k-pad cols 90..95 of all 16 rows = 0 (region aliased VH until now).
  // (cols 96..103 are never read: b128 A-reads reach col 95 max.)
  if (wtid < 48){
    int row = wtid/3, j = wtid - 3*row;
    ((unsigned*)sm)[(X90>>1) + row*(S_X9>>1) + 45 + j] = 0u;
  }

  // ---- stage 4: PFF30 -> x90 (KT/VH dead; X90 pads zeroed above) ----
  pff30<true>(sm, wtid, wf, b1, b2, g_pff, b_pff);
  // ---- stage 5: PFF90 (x90 in-place; H90 aliases X30 — dead after stage 4) ----
  pff90(sm, wtid, wf, b1p, b2p, g_pff1, b_pff1);
  // ---- classifier + softmax ----
  classifier(sm, wtid, wf, bc1, Wc2, bc2, out, row0);
}

extern "C" void kernel_launch(void* const* d_in, const int* in_sizes, int n_in,
                              void* d_out, int out_size, void* d_ws, size_t ws_size,
                              hipStream_t stream)
{
  const float* q     = (const float*)d_in[0];
  const float* k     = (const float*)d_in[1];
  const float* v     = (const float*)d_in[2];
  const float* Wq    = (const float*)d_in[3];
  const float* Wk    = (const float*)d_in[4];
  const float* Wv    = (const float*)d_in[5];
  const float* g_mha = (const float*)d_in[6];
  const float* b_mha = (const float*)d_in[7];
  const float* W1    = (const float*)d_in[8];
  const float* b1    = (const float*)d_in[9];
  const float* W2    = (const float*)d_in[10];
  const float* b2    = (const float*)d_in[11];
  const float* g_pff = (const float*)d_in[12];
  const float* b_pff = (const float*)d_in[13];
  const float* W1p   = (const float*)d_in[14];
  const float* b1p   = (const float*)d_in[15];
  const float* W2p   = (const float*)d_in[16];
  const float* b2p   = (const float*)d_in[17];
  const float* g_pff1= (const float*)d_in[18];
  const float* b_pff1= (const float*)d_in[19];
  const float* Wc1   = (const float*)d_in[20];
  const float* bc1   = (const float*)d_in[21];
  const float* Wc2   = (const float*)d_in[22];
  const float* bc2   = (const float*)d_in[23];

  unsigned short* wf = (unsigned short*)d_ws;
  const int nrows = in_sizes[0] / 90;

  hipLaunchKernelGGL(prep_kernel, dim3((NFRAG*512 + 255)/256), dim3(256), 0, stream,
                     Wq, Wk, Wv, W1, W2, W1p, W2p, Wc1, wf);

  hipLaunchKernelGGL(moct_kernel, dim3(nrows/32), dim3(128), 0, stream,
    q, k, v, g_mha, b_mha, b1, b2, g_pff, b_pff,
    b1p, b2p, g_pff1, b_pff1, bc1, Wc2, bc2, wf, (float*)d_out);
}